// Round 8
// baseline (199.278 us; speedup 1.0000x reference)
//
#include <hip/hip_runtime.h>
#include <hip/hip_bf16.h>
#include <cmath>

#define B_SZ 4
#define N_SEQ 2048
#define DIM 512
#define NH 8
#define DH 64
#define QKV_N 1536
#define ROWS (B_SZ * N_SEQ)   // 8192

typedef __bf16 bf16x8 __attribute__((ext_vector_type(8)));
typedef __bf16 bf16x4 __attribute__((ext_vector_type(4)));
typedef float  f32x4  __attribute__((ext_vector_type(4)));

#define GLOAD_LDS16(gp, lp)                                                     \
    __builtin_amdgcn_global_load_lds(                                           \
        (const __attribute__((address_space(1))) void*)(gp),                    \
        (__attribute__((address_space(3))) void*)(lp), 16, 0, 0)

#define MFMA_BF16 __builtin_amdgcn_mfma_f32_16x16x32_bf16

// ---------------- cos/sin table: cs[pos][p] = {cos,sin}(pos * 10000^(-p/32))
__global__ __launch_bounds__(256) void cs_kernel(float2* __restrict__ cs) {
    int idx = blockIdx.x * 256 + threadIdx.x;   // 2048*32
    int pos = idx >> 5, p = idx & 31;
    float ang = (float)pos * exp2f(-0.41524101186092028f * (float)p);
    float sn, c;
    sincosf(ang, &sn, &c);
    cs[idx] = make_float2(c, sn);
}

// ---------------- fused RMS-norm + gamma + bf16 cast: A[row] = bf16(x * gamma * s)
__global__ __launch_bounds__(64) void rmscast_kernel(const float* __restrict__ x,
                                                     const float* __restrict__ gamma,
                                                     __bf16* __restrict__ A) {
    int row = blockIdx.x;
    int t = threadIdx.x;
    const float4* xr = (const float4*)(x + (size_t)row * DIM);
    float4 a = xr[t];
    float4 b = xr[t + 64];
    float ss = a.x*a.x + a.y*a.y + a.z*a.z + a.w*a.w
             + b.x*b.x + b.y*b.y + b.z*b.z + b.w*b.w;
    #pragma unroll
    for (int off = 32; off > 0; off >>= 1) ss += __shfl_xor(ss, off, 64);
    float s = 22.62741699796952f / fmaxf(sqrtf(ss), 1e-8f);   // sqrt(512)/max(norm,eps)
    const float4* gr = (const float4*)gamma;
    float4 g1 = gr[t], g2 = gr[t + 64];
    bf16x4 o1 = { (__bf16)(a.x*g1.x*s), (__bf16)(a.y*g1.y*s),
                  (__bf16)(a.z*g1.z*s), (__bf16)(a.w*g1.w*s) };
    bf16x4 o2 = { (__bf16)(b.x*g2.x*s), (__bf16)(b.y*g2.y*s),
                  (__bf16)(b.z*g2.z*s), (__bf16)(b.w*g2.w*s) };
    *(bf16x4*)(A + (size_t)row * DIM + t * 4)       = o1;
    *(bf16x4*)(A + (size_t)row * DIM + 256 + t * 4) = o2;
}

// ---------------- transpose + bf16 cast of BOTH weights in one launch.
__device__ __forceinline__ void tcast_tile(const float* __restrict__ W,
                                           __bf16* __restrict__ Wt,
                                           int K, int N, int n0, int k0, int t,
                                           float (*Ls)[68]) {
    const int tx = t & 15, ty = t >> 4;
    #pragma unroll
    for (int i = 0; i < 4; i++) {
        int k = ty + i * 16;
        float4 v = *(const float4*)&W[(size_t)(k0 + k) * N + n0 + tx * 4];
        *(float4*)&Ls[k][tx * 4] = v;
    }
    __syncthreads();
    const int nrow = t >> 2, seg = (t & 3) * 16;
    bf16x8 o0, o1;
    #pragma unroll
    for (int j = 0; j < 8; j++) o0[j] = (__bf16)Ls[seg + j][nrow];
    #pragma unroll
    for (int j = 0; j < 8; j++) o1[j] = (__bf16)Ls[seg + 8 + j][nrow];
    *(bf16x8*)&Wt[(size_t)(n0 + nrow) * K + k0 + seg]     = o0;
    *(bf16x8*)&Wt[(size_t)(n0 + nrow) * K + k0 + seg + 8] = o1;
}

__global__ __launch_bounds__(256) void tcast2_kernel(const float* __restrict__ w_qkv,
                                                     const float* __restrict__ w_out,
                                                     __bf16* __restrict__ Wqkvt,
                                                     __bf16* __restrict__ Woutt) {
    __shared__ float Ls[64][68];
    const int bx = blockIdx.x, k0 = blockIdx.y * 64, t = threadIdx.x;
    if (bx < 24) tcast_tile(w_qkv, Wqkvt, DIM, QKV_N, bx * 64, k0, t, Ls);
    else         tcast_tile(w_out, Woutt, DIM, DIM, (bx - 24) * 64, k0, t, Ls);
}

// ---------------- bf16 MFMA GEMM (m97 structure): C[M,N] = A[M,512] @ Bt[N,512]^T
template <int N, typename OutT>
__global__ __launch_bounds__(256) void gemm_bf16_kernel(const __bf16* __restrict__ A,
                                                        const __bf16* __restrict__ Bt,
                                                        OutT* __restrict__ C) {
    __shared__ __bf16 As[128 * 32];
    __shared__ __bf16 Bs[128 * 32];
    const int t = threadIdx.x;
    const int lane = t & 63;
    const int w = t >> 6;
    const int l16 = lane & 15, quad = lane >> 4;
    const int wr = w >> 1, wc = w & 1;
    const int row0 = blockIdx.y * 128, col0 = blockIdx.x * 128;

    f32x4 acc[4][4] = {};

    const int r0a = t >> 2,         ks0 = (t & 3) * 8;
    const int r1a = (t + 256) >> 2, ks1 = (t & 3) * 8;

    for (int kt = 0; kt < DIM; kt += 32) {
        __syncthreads();
        GLOAD_LDS16(A  + (size_t)(row0 + r0a) * DIM + kt + ks0, As + t * 8);
        GLOAD_LDS16(A  + (size_t)(row0 + r1a) * DIM + kt + ks1, As + (t + 256) * 8);
        GLOAD_LDS16(Bt + (size_t)(col0 + r0a) * DIM + kt + ks0, Bs + t * 8);
        GLOAD_LDS16(Bt + (size_t)(col0 + r1a) * DIM + kt + ks1, Bs + (t + 256) * 8);
        __syncthreads();
        bf16x8 af[4], bfr[4];
        #pragma unroll
        for (int mi = 0; mi < 4; mi++)
            af[mi] = *(const bf16x8*)(As + (wr * 64 + mi * 16 + l16) * 32 + quad * 8);
        #pragma unroll
        for (int ni = 0; ni < 4; ni++)
            bfr[ni] = *(const bf16x8*)(Bs + (wc * 64 + ni * 16 + l16) * 32 + quad * 8);
        #pragma unroll
        for (int mi = 0; mi < 4; mi++)
            #pragma unroll
            for (int ni = 0; ni < 4; ni++)
                acc[mi][ni] = MFMA_BF16(af[mi], bfr[ni], acc[mi][ni], 0, 0, 0);
    }
    #pragma unroll
    for (int mi = 0; mi < 4; mi++) {
        #pragma unroll
        for (int ni = 0; ni < 4; ni++) {
            #pragma unroll
            for (int r = 0; r < 4; r++) {
                int m = row0 + wr * 64 + mi * 16 + quad * 4 + r;
                int n = col0 + wc * 64 + ni * 16 + l16;
                if constexpr (sizeof(OutT) == 4) {
                    C[(size_t)m * N + n] = acc[mi][ni][r];
                } else {
                    C[(size_t)m * N + n] = (__bf16)acc[mi][ni][r];
                }
            }
        }
    }
}

// ---------------- QKV GEMM with FUSED prep epilogue.
// Same main loop; epilogue applies RoPE on fp32 accumulators (partner value via
// __shfl_xor(.,1): adjacent l16 lanes hold adjacent columns = the RoPE pair) and
// stores directly into Qb (row-major head-major) / Kf / Vf (MFMA-fragment layouts,
// identical index algebra to the R5-verified prep/attn pair). blockIdx.x>>2 picks
// region (0=Q,1=K,2=V) — uniform per block, no divergence.
__global__ __launch_bounds__(256) void gemm_qkv_kernel(const __bf16* __restrict__ A,
                                                       const __bf16* __restrict__ Bt,
                                                       const float2* __restrict__ cstab,
                                                       __bf16* __restrict__ Qb,
                                                       __bf16* __restrict__ Kf,
                                                       __bf16* __restrict__ Vf) {
    __shared__ __bf16 As[128 * 32];
    __shared__ __bf16 Bs[128 * 32];
    const int t = threadIdx.x;
    const int lane = t & 63;
    const int w = t >> 6;
    const int l16 = lane & 15, quad = lane >> 4;
    const int wr = w >> 1, wc = w & 1;
    const int row0 = blockIdx.y * 128, col0 = blockIdx.x * 128;

    f32x4 acc[4][4] = {};

    const int r0a = t >> 2,         ks0 = (t & 3) * 8;
    const int r1a = (t + 256) >> 2, ks1 = (t & 3) * 8;

    for (int kt = 0; kt < DIM; kt += 32) {
        __syncthreads();
        GLOAD_LDS16(A  + (size_t)(row0 + r0a) * DIM + kt + ks0, As + t * 8);
        GLOAD_LDS16(A  + (size_t)(row0 + r1a) * DIM + kt + ks1, As + (t + 256) * 8);
        GLOAD_LDS16(Bt + (size_t)(col0 + r0a) * DIM + kt + ks0, Bs + t * 8);
        GLOAD_LDS16(Bt + (size_t)(col0 + r1a) * DIM + kt + ks1, Bs + (t + 256) * 8);
        __syncthreads();
        bf16x8 af[4], bfr[4];
        #pragma unroll
        for (int mi = 0; mi < 4; mi++)
            af[mi] = *(const bf16x8*)(As + (wr * 64 + mi * 16 + l16) * 32 + quad * 8);
        #pragma unroll
        for (int ni = 0; ni < 4; ni++)
            bfr[ni] = *(const bf16x8*)(Bs + (wc * 64 + ni * 16 + l16) * 32 + quad * 8);
        #pragma unroll
        for (int mi = 0; mi < 4; mi++)
            #pragma unroll
            for (int ni = 0; ni < 4; ni++)
                acc[mi][ni] = MFMA_BF16(af[mi], bfr[ni], acc[mi][ni], 0, 0, 0);
    }

    const int region = blockIdx.x >> 2;          // 0=Q, 1=K, 2=V
    const float QSCALE = 0.18033688011112042f;   // 0.125 * log2(e)
    #pragma unroll
    for (int mi = 0; mi < 4; mi++) {
        #pragma unroll
        for (int r = 0; r < 4; r++) {
            const int m   = row0 + wr * 64 + mi * 16 + quad * 4 + r;
            const int bb  = m >> 11;
            const int pos = m & (N_SEQ - 1);
            const int nt  = pos >> 6;
            #pragma unroll
            for (int ni = 0; ni < 4; ni++) {
                const int c  = col0 + wc * 64 + ni * 16 + l16;
                const int d  = c & 63;
                const int bh = bb * 8 + ((c >> 6) & 7);
                float v = acc[mi][ni][r];
                if (region == 2) {
                    const int keyloc = pos & 63;
                    Vf[((size_t)bh * 32 + nt) * 4096
                       + ((d >> 4) * 2 + (keyloc >> 5)) * 512
                       + ((((keyloc >> 3) & 3) * 16 + (d & 15)) * 8) + (keyloc & 7)]
                        = (__bf16)v;
                } else {
                    float2 cssn = cstab[pos * 32 + (d >> 1)];
                    float pr = __shfl_xor(v, 1);
                    float o = (d & 1) ? (v * cssn.x + pr * cssn.y)
                                      : (v * cssn.x - pr * cssn.y);
                    if (region == 0) {
                        Qb[((size_t)bh * N_SEQ + pos) * DH + d] = (__bf16)(o * QSCALE);
                    } else {
                        Kf[((size_t)bh * 32 + nt) * 4096
                           + (((pos >> 4) & 3) * 2 + (d >> 5)) * 512
                           + ((((d >> 3) & 3) * 16 + (pos & 15)) * 8) + (d & 7)]
                            = (__bf16)o;
                    }
                }
            }
        }
    }
}

// ---------------- MFMA flash attention (R5-proven structure, exp2 variant).
// Block = 4 waves x 32 q; grid = qc*32+bh (bx%8 = head -> XCD-local KV, L2-resident).
// Per 64-key tile: K+V (16 KB) DMA'd into LDS once (global_load_lds, double-buffered,
// prefetch-before-wait vmcnt(4)), shared by all 4 waves. No-max softmax (exp2,
// log2e folded into Q); row-sum via MFMA vs all-ones; P roundtrip via wave-private LDS.
__global__ __launch_bounds__(256, 2) void attn_mfma_kernel(const __bf16* __restrict__ Qb,
                                                           const __bf16* __restrict__ Kf,
                                                           const __bf16* __restrict__ Vf,
                                                           __bf16* __restrict__ attn) {
    __shared__ __bf16 kv[2][8192];           // [buf][K 4096 | V 4096]  = 32 KB
    __shared__ __bf16 plds[4][2][16][68];    // per-wave, per-qfrag P   = 17 KB

    const int t    = threadIdx.x;
    const int w    = t >> 6;
    const int lane = t & 63;
    const int l16  = lane & 15;
    const int quad = lane >> 4;

    const int bx = blockIdx.x;     // qc*32 + bh
    const int bh = bx & 31;
    const int qc = bx >> 5;        // 0..15
    const int b  = bh >> 3;
    const int h  = bh & 7;

    const int qrow = qc * 128 + w * 32;
    const __bf16* Qh = Qb + ((size_t)bh * N_SEQ + qrow) * DH;
    const __bf16* Kt = Kf + (size_t)bh * 32 * 4096;
    const __bf16* Vt = Vf + (size_t)bh * 32 * 4096;

    bf16x8 qa[2][2];
    #pragma unroll
    for (int f = 0; f < 2; f++) {
        qa[f][0] = *(const bf16x8*)(Qh + (size_t)(f * 16 + l16) * DH + quad * 8);
        qa[f][1] = *(const bf16x8*)(Qh + (size_t)(f * 16 + l16) * DH + 32 + quad * 8);
    }

    bf16x8 ones;
    #pragma unroll
    for (int i = 0; i < 8; i++) ones[i] = (__bf16)1.0f;

    f32x4 O[2][4] = {};
    f32x4 L[2] = {};

    auto dma_tile = [&](int tt, int bb) {
        const __bf16* kss = Kt + (size_t)tt * 4096;
        const __bf16* vss = Vt + (size_t)tt * 4096;
        GLOAD_LDS16(kss + w * 512 + lane * 8,       &kv[bb][w * 512 + lane * 8]);
        GLOAD_LDS16(kss + (w + 4) * 512 + lane * 8, &kv[bb][(w + 4) * 512 + lane * 8]);
        GLOAD_LDS16(vss + w * 512 + lane * 8,       &kv[bb][4096 + w * 512 + lane * 8]);
        GLOAD_LDS16(vss + (w + 4) * 512 + lane * 8, &kv[bb][4096 + (w + 4) * 512 + lane * 8]);
    };

    dma_tile(0, 0);
    for (int tt = 0; tt < 32; tt++) {
        const int cur = tt & 1;
        __syncthreads();                       // all waves done with buf[cur^1]
        if (tt + 1 < 32) {
            dma_tile(tt + 1, cur ^ 1);         // prefetch
            asm volatile("s_waitcnt vmcnt(4)" ::: "memory");   // drain tile tt only
        } else {
            asm volatile("s_waitcnt vmcnt(0)" ::: "memory");
        }
        __syncthreads();                       // publish tile tt to all waves

        const __bf16* kb = kv[cur];
        const __bf16* vb = kv[cur] + 4096;

        bf16x8 kf[4][2];
        #pragma unroll
        for (int g = 0; g < 4; g++)
            #pragma unroll
            for (int c = 0; c < 2; c++)
                kf[g][c] = *(const bf16x8*)(kb + (g * 2 + c) * 512 + lane * 8);
        bf16x8 vf[4][2];
        #pragma unroll
        for (int n = 0; n < 4; n++)
            #pragma unroll
            for (int kc = 0; kc < 2; kc++)
                vf[n][kc] = *(const bf16x8*)(vb + (n * 2 + kc) * 512 + lane * 8);

        #pragma unroll
        for (int f = 0; f < 2; f++) {
            f32x4 S[4];
            #pragma unroll
            for (int g = 0; g < 4; g++) {
                f32x4 z = {0, 0, 0, 0};
                z = MFMA_BF16(qa[f][0], kf[g][0], z, 0, 0, 0);
                z = MFMA_BF16(qa[f][1], kf[g][1], z, 0, 0, 0);
                S[g] = z;
            }
            #pragma unroll
            for (int g = 0; g < 4; g++)
                #pragma unroll
                for (int r = 0; r < 4; r++)
                    plds[w][f][quad * 4 + r][g * 16 + l16] = (__bf16)exp2f(S[g][r]);
        }
        asm volatile("s_waitcnt lgkmcnt(0)" ::: "memory");
        #pragma unroll
        for (int f = 0; f < 2; f++) {
            bf16x8 pa0 = *(const bf16x8*)&plds[w][f][l16][quad * 8];
            bf16x8 pa1 = *(const bf16x8*)&plds[w][f][l16][32 + quad * 8];
            #pragma unroll
            for (int n = 0; n < 4; n++) {
                O[f][n] = MFMA_BF16(pa0, vf[n][0], O[f][n], 0, 0, 0);
                O[f][n] = MFMA_BF16(pa1, vf[n][1], O[f][n], 0, 0, 0);
            }
            L[f] = MFMA_BF16(pa0, ones, L[f], 0, 0, 0);
            L[f] = MFMA_BF16(pa1, ones, L[f], 0, 0, 0);
        }
    }

    #pragma unroll
    for (int f = 0; f < 2; f++) {
        float inv[4];
        #pragma unroll
        for (int r = 0; r < 4; r++) inv[r] = 1.0f / L[f][r];
        #pragma unroll
        for (int n = 0; n < 4; n++)
            #pragma unroll
            for (int r = 0; r < 4; r++) {
                size_t row = (size_t)(b * N_SEQ + qrow + f * 16 + quad * 4 + r);
                attn[row * 512 + h * DH + n * 16 + l16] = (__bf16)(O[f][n][r] * inv[r]);
            }
    }
}

extern "C" void kernel_launch(void* const* d_in, const int* in_sizes, int n_in,
                              void* d_out, int out_size, void* d_ws, size_t ws_size,
                              hipStream_t stream) {
    const float* x     = (const float*)d_in[0];
    const float* gamma = (const float*)d_in[1];
    const float* w_qkv = (const float*)d_in[2];
    const float* w_out = (const float*)d_in[3];
    float* out = (float*)d_out;

    // workspace (bf16): Abf 8.4MB (attnb aliases it after gemm_qkv) | Wqkvt 1.5 |
    // Woutt 0.5 | Qb,Kf,Vf 8.4 each | cstab 0.5 (f32x2).  ~36 MB total.
    __bf16* Abf   = (__bf16*)d_ws;
    __bf16* attnb = Abf;
    __bf16* Wqkvt = Abf + (size_t)ROWS * DIM;
    __bf16* Woutt = Wqkvt + (size_t)QKV_N * DIM;
    __bf16* Qb    = Woutt + (size_t)DIM * DIM;
    __bf16* Kf    = Qb + (size_t)NH * B_SZ * N_SEQ * DH;
    __bf16* Vf    = Kf + (size_t)NH * B_SZ * N_SEQ * DH;
    float2* cstab = (float2*)(Vf + (size_t)NH * B_SZ * N_SEQ * DH);

    cs_kernel<<<256, 256, 0, stream>>>(cstab);
    rmscast_kernel<<<ROWS, 64, 0, stream>>>(x, gamma, Abf);
    tcast2_kernel<<<dim3(32, 8), 256, 0, stream>>>(w_qkv, w_out, Wqkvt, Woutt);
    gemm_qkv_kernel<<<dim3(QKV_N / 128, ROWS / 128), 256, 0, stream>>>(
        Abf, Wqkvt, cstab, Qb, Kf, Vf);
    attn_mfma_kernel<<<512, 256, 0, stream>>>(Qb, Kf, Vf, attnb);
    gemm_bf16_kernel<DIM, float><<<dim3(DIM / 128, ROWS / 128), 256, 0, stream>>>(
        attnb, Woutt, out);
}

// Round 9
// 175.740 us; speedup vs baseline: 1.1339x; 1.1339x over previous
//
#include <hip/hip_runtime.h>
#include <hip/hip_bf16.h>
#include <cmath>

#define B_SZ 4
#define N_SEQ 2048
#define DIM 512
#define NH 8
#define DH 64
#define QKV_N 1536
#define ROWS (B_SZ * N_SEQ)   // 8192

typedef __bf16 bf16x8 __attribute__((ext_vector_type(8)));
typedef __bf16 bf16x4 __attribute__((ext_vector_type(4)));
typedef float  f32x4  __attribute__((ext_vector_type(4)));

#define GLOAD_LDS16(gp, lp)                                                     \
    __builtin_amdgcn_global_load_lds(                                           \
        (const __attribute__((address_space(1))) void*)(gp),                    \
        (__attribute__((address_space(3))) void*)(lp), 16, 0, 0)

#define MFMA_BF16 __builtin_amdgcn_mfma_f32_16x16x32_bf16

// ---------------- fused RMS-norm + gamma + bf16 cast: A[row] = bf16(x * gamma * s)
__global__ __launch_bounds__(64) void rmscast_kernel(const float* __restrict__ x,
                                                     const float* __restrict__ gamma,
                                                     __bf16* __restrict__ A) {
    int row = blockIdx.x;
    int t = threadIdx.x;
    const float4* xr = (const float4*)(x + (size_t)row * DIM);
    float4 a = xr[t];
    float4 b = xr[t + 64];
    float ss = a.x*a.x + a.y*a.y + a.z*a.z + a.w*a.w
             + b.x*b.x + b.y*b.y + b.z*b.z + b.w*b.w;
    #pragma unroll
    for (int off = 32; off > 0; off >>= 1) ss += __shfl_xor(ss, off, 64);
    float s = 22.62741699796952f / fmaxf(sqrtf(ss), 1e-8f);   // sqrt(512)/max(norm,eps)
    const float4* gr = (const float4*)gamma;
    float4 g1 = gr[t], g2 = gr[t + 64];
    bf16x4 o1 = { (__bf16)(a.x*g1.x*s), (__bf16)(a.y*g1.y*s),
                  (__bf16)(a.z*g1.z*s), (__bf16)(a.w*g1.w*s) };
    bf16x4 o2 = { (__bf16)(b.x*g2.x*s), (__bf16)(b.y*g2.y*s),
                  (__bf16)(b.z*g2.z*s), (__bf16)(b.w*g2.w*s) };
    *(bf16x4*)(A + (size_t)row * DIM + t * 4)       = o1;
    *(bf16x4*)(A + (size_t)row * DIM + 256 + t * 4) = o2;
}

// ---------------- transpose + bf16 cast of BOTH weights in one launch.
__device__ __forceinline__ void tcast_tile(const float* __restrict__ W,
                                           __bf16* __restrict__ Wt,
                                           int K, int N, int n0, int k0, int t,
                                           float (*Ls)[68]) {
    const int tx = t & 15, ty = t >> 4;
    #pragma unroll
    for (int i = 0; i < 4; i++) {
        int k = ty + i * 16;
        float4 v = *(const float4*)&W[(size_t)(k0 + k) * N + n0 + tx * 4];
        *(float4*)&Ls[k][tx * 4] = v;
    }
    __syncthreads();
    const int nrow = t >> 2, seg = (t & 3) * 16;
    bf16x8 o0, o1;
    #pragma unroll
    for (int j = 0; j < 8; j++) o0[j] = (__bf16)Ls[seg + j][nrow];
    #pragma unroll
    for (int j = 0; j < 8; j++) o1[j] = (__bf16)Ls[seg + 8 + j][nrow];
    *(bf16x8*)&Wt[(size_t)(n0 + nrow) * K + k0 + seg]     = o0;
    *(bf16x8*)&Wt[(size_t)(n0 + nrow) * K + k0 + seg + 8] = o1;
}

__global__ __launch_bounds__(256) void tcast2_kernel(const float* __restrict__ w_qkv,
                                                     const float* __restrict__ w_out,
                                                     __bf16* __restrict__ Wqkvt,
                                                     __bf16* __restrict__ Woutt) {
    __shared__ float Ls[64][68];
    const int bx = blockIdx.x, k0 = blockIdx.y * 64, t = threadIdx.x;
    if (bx < 24) tcast_tile(w_qkv, Wqkvt, DIM, QKV_N, bx * 64, k0, t, Ls);
    else         tcast_tile(w_out, Woutt, DIM, DIM, (bx - 24) * 64, k0, t, Ls);
}

// ---------------- bf16 MFMA GEMM (m97 structure): C[M,N] = A[M,512] @ Bt[N,512]^T
template <int N, typename OutT>
__global__ __launch_bounds__(256) void gemm_bf16_kernel(const __bf16* __restrict__ A,
                                                        const __bf16* __restrict__ Bt,
                                                        OutT* __restrict__ C) {
    __shared__ __bf16 As[128 * 32];
    __shared__ __bf16 Bs[128 * 32];
    const int t = threadIdx.x;
    const int lane = t & 63;
    const int w = t >> 6;
    const int l16 = lane & 15, quad = lane >> 4;
    const int wr = w >> 1, wc = w & 1;
    const int row0 = blockIdx.y * 128, col0 = blockIdx.x * 128;

    f32x4 acc[4][4] = {};

    const int r0a = t >> 2,         ks0 = (t & 3) * 8;
    const int r1a = (t + 256) >> 2, ks1 = (t & 3) * 8;

    for (int kt = 0; kt < DIM; kt += 32) {
        __syncthreads();
        GLOAD_LDS16(A  + (size_t)(row0 + r0a) * DIM + kt + ks0, As + t * 8);
        GLOAD_LDS16(A  + (size_t)(row0 + r1a) * DIM + kt + ks1, As + (t + 256) * 8);
        GLOAD_LDS16(Bt + (size_t)(col0 + r0a) * DIM + kt + ks0, Bs + t * 8);
        GLOAD_LDS16(Bt + (size_t)(col0 + r1a) * DIM + kt + ks1, Bs + (t + 256) * 8);
        __syncthreads();
        bf16x8 af[4], bfr[4];
        #pragma unroll
        for (int mi = 0; mi < 4; mi++)
            af[mi] = *(const bf16x8*)(As + (wr * 64 + mi * 16 + l16) * 32 + quad * 8);
        #pragma unroll
        for (int ni = 0; ni < 4; ni++)
            bfr[ni] = *(const bf16x8*)(Bs + (wc * 64 + ni * 16 + l16) * 32 + quad * 8);
        #pragma unroll
        for (int mi = 0; mi < 4; mi++)
            #pragma unroll
            for (int ni = 0; ni < 4; ni++)
                acc[mi][ni] = MFMA_BF16(af[mi], bfr[ni], acc[mi][ni], 0, 0, 0);
    }
    #pragma unroll
    for (int mi = 0; mi < 4; mi++) {
        #pragma unroll
        for (int ni = 0; ni < 4; ni++) {
            #pragma unroll
            for (int r = 0; r < 4; r++) {
                int m = row0 + wr * 64 + mi * 16 + quad * 4 + r;
                int n = col0 + wc * 64 + ni * 16 + l16;
                if constexpr (sizeof(OutT) == 4) {
                    C[(size_t)m * N + n] = acc[mi][ni][r];
                } else {
                    C[(size_t)m * N + n] = (__bf16)acc[mi][ni][r];
                }
            }
        }
    }
}

// ---------------- Prep: fused RoPE + head-major bf16 Q + PRE-FRAGMENTED K and V^T.
// Q scale = 0.125 * log2(e): attention uses raw v_exp_f32 (exp2) directly.
__global__ __launch_bounds__(256) void prep_kernel(const __bf16* __restrict__ qkvb,
                                                   __bf16* __restrict__ Qb,
                                                   __bf16* __restrict__ Kf,
                                                   __bf16* __restrict__ Vf) {
    const int bx = blockIdx.x;   // bh*32 + ntile
    const int nt = bx & 31;
    const int bh = bx >> 5;
    const int b  = bh >> 3;
    const int h  = bh & 7;
    const int t  = threadIdx.x;
    const float QSCALE = 0.18033688011112042f;   // 0.125 * log2(e)

    {   // Q/K rope: thread t -> row r = t>>2, dims d0 = (t&3)*16 (8 pairs)
        const int r  = t >> 2;
        const int d0 = (t & 3) << 4;
        const int pos = nt * 64 + r;
        const __bf16* qp = qkvb + (size_t)(b * N_SEQ + pos) * QKV_N + h * DH + d0;

        union Pack { __bf16 h[16]; uint4 u[2]; };
        Pack qi, ki, qo, ko;
        qi.u[0] = ((const uint4*)qp)[0];         qi.u[1] = ((const uint4*)qp)[1];
        ki.u[0] = ((const uint4*)(qp + 512))[0]; ki.u[1] = ((const uint4*)(qp + 512))[1];

        #pragma unroll
        for (int i = 0; i < 8; i++) {
            int p = (d0 >> 1) + i;
            float inv = exp2f(-0.41524101186092028f * (float)p);  // 10000^(-p/32)
            float ang = (float)pos * inv;
            float sn, cs;
            sincosf(ang, &sn, &cs);
            float qe = (float)qi.h[2*i], qd = (float)qi.h[2*i+1];
            float ke = (float)ki.h[2*i], kd = (float)ki.h[2*i+1];
            qo.h[2*i]   = (__bf16)(QSCALE * (qe * cs - qd * sn));
            qo.h[2*i+1] = (__bf16)(QSCALE * (qd * cs + qe * sn));
            ko.h[2*i]   = (__bf16)(ke * cs - kd * sn);
            ko.h[2*i+1] = (__bf16)(kd * cs + ke * sn);
        }
        // Q: row-major
        uint4* qd_ = (uint4*)(Qb + ((size_t)bh * N_SEQ + pos) * DH + d0);
        qd_[0] = qo.u[0]; qd_[1] = qo.u[1];
        // K: fragmented (chunk (g*2+c), elem (quad*16+kl)*8+j)
        const int group = r >> 4, kl = r & 15;
        const int c = d0 >> 5, quad = (d0 & 31) >> 3;
        __bf16* kdst = Kf + ((size_t)bh * 32 + nt) * 4096
                          + (group * 2 + c) * 512 + (quad * 16 + kl) * 8;
        *(uint4*)kdst         = ko.u[0];
        *(uint4*)(kdst + 128) = ko.u[1];   // quad+1
    }

    {   // V: wave w -> keys w*16..+15, lane = dim 0..63; write fragmented V^T
        const int w = t >> 6, lane = t & 63;
        union Pack { __bf16 h[16]; uint4 u[2]; };
        Pack v;
        #pragma unroll
        for (int j = 0; j < 16; j++) {
            int row = nt * 64 + w * 16 + j;
            v.h[j] = qkvb[(size_t)(b * N_SEQ + row) * QKV_N + 1024 + h * DH + lane];
        }
        const int ng = lane >> 4, vl = lane & 15;
        __bf16* vdst = Vf + ((size_t)bh * 32 + nt) * 4096
                          + (ng * 2 + (w >> 1)) * 512 + (((w & 1) * 2) * 16 + vl) * 8;
        *(uint4*)vdst         = v.u[0];
        *(uint4*)(vdst + 128) = v.u[1];    // quad+1
    }
}

// ---------------- MFMA flash attention (R5 double-buffer shape, 128-key tiles).
// Block = 4 waves x 32 q; grid = qc*32+bh (bx%8 = head -> XCD-local KV, L2-resident).
// Per 128-key tile: K+V (32 KB) DMA'd once into LDS (global_load_lds, double-buffered,
// prefetch-before-wait vmcnt(8)), shared by all 4 waves -> HALF the barrier events of
// the 64-key version. No-max softmax via raw v_exp_f32 (__builtin_amdgcn_exp2f; log2e
// pre-folded into Q; |S|<~12 so no range handling needed). Row-sum via MFMA vs
// all-ones. P roundtrips through a single wave-private LDS buffer reused across the
// 4 (half,qfrag) passes — per-wave DS ops are in-order, so WAR needs no barrier.
__global__ __launch_bounds__(256, 2) void attn_mfma_kernel(const __bf16* __restrict__ Qb,
                                                           const __bf16* __restrict__ Kf,
                                                           const __bf16* __restrict__ Vf,
                                                           __bf16* __restrict__ attn) {
    __shared__ __bf16 kv[2][16384];      // [buf][K0 K1 V0 V1]  = 64 KB
    __shared__ __bf16 plds[4][16][68];   // per-wave P buffer   = 8.7 KB

    const int t    = threadIdx.x;
    const int w    = t >> 6;
    const int lane = t & 63;
    const int l16  = lane & 15;
    const int quad = lane >> 4;

    const int bx = blockIdx.x;     // qc*32 + bh
    const int bh = bx & 31;
    const int qc = bx >> 5;        // 0..15
    const int b  = bh >> 3;
    const int h  = bh & 7;

    const int qrow = qc * 128 + w * 32;
    const __bf16* Qh = Qb + ((size_t)bh * N_SEQ + qrow) * DH;
    const __bf16* Kt = Kf + (size_t)bh * 32 * 4096;
    const __bf16* Vt = Vf + (size_t)bh * 32 * 4096;

    bf16x8 qa[2][2];
    #pragma unroll
    for (int f = 0; f < 2; f++) {
        qa[f][0] = *(const bf16x8*)(Qh + (size_t)(f * 16 + l16) * DH + quad * 8);
        qa[f][1] = *(const bf16x8*)(Qh + (size_t)(f * 16 + l16) * DH + 32 + quad * 8);
    }

    bf16x8 ones;
    #pragma unroll
    for (int i = 0; i < 8; i++) ones[i] = (__bf16)1.0f;

    f32x4 O[2][4] = {};
    f32x4 L[2] = {};

    auto dma_tile = [&](int tt, int bb) {    // tt = 128-key tile index (0..15)
        const __bf16* kss = Kt + (size_t)tt * 8192;
        const __bf16* vss = Vt + (size_t)tt * 8192;
        #pragma unroll
        for (int seg = 0; seg < 2; seg++) {
            GLOAD_LDS16(kss + seg * 4096 + w * 512 + lane * 8,
                        &kv[bb][seg * 4096 + w * 512 + lane * 8]);
            GLOAD_LDS16(kss + seg * 4096 + (w + 4) * 512 + lane * 8,
                        &kv[bb][seg * 4096 + (w + 4) * 512 + lane * 8]);
            GLOAD_LDS16(vss + seg * 4096 + w * 512 + lane * 8,
                        &kv[bb][8192 + seg * 4096 + w * 512 + lane * 8]);
            GLOAD_LDS16(vss + seg * 4096 + (w + 4) * 512 + lane * 8,
                        &kv[bb][8192 + seg * 4096 + (w + 4) * 512 + lane * 8]);
        }
    };

    dma_tile(0, 0);
    for (int tt = 0; tt < 16; tt++) {
        const int cur = tt & 1;
        __syncthreads();                       // all waves done with buf[cur^1]
        if (tt + 1 < 16) {
            dma_tile(tt + 1, cur ^ 1);         // prefetch (8 loads stay in flight)
            asm volatile("s_waitcnt vmcnt(8)" ::: "memory");   // drain tile tt only
        } else {
            asm volatile("s_waitcnt vmcnt(0)" ::: "memory");
        }
        __syncthreads();                       // publish tile tt to all waves

        #pragma unroll
        for (int hh = 0; hh < 2; hh++) {       // two 64-key halves of the tile
            const __bf16* kb = kv[cur] + hh * 4096;
            const __bf16* vb = kv[cur] + 8192 + hh * 4096;

            bf16x8 kf[4][2];
            #pragma unroll
            for (int g = 0; g < 4; g++)
                #pragma unroll
                for (int c = 0; c < 2; c++)
                    kf[g][c] = *(const bf16x8*)(kb + (g * 2 + c) * 512 + lane * 8);
            bf16x8 vf[4][2];
            #pragma unroll
            for (int n = 0; n < 4; n++)
                #pragma unroll
                for (int kc = 0; kc < 2; kc++)
                    vf[n][kc] = *(const bf16x8*)(vb + (n * 2 + kc) * 512 + lane * 8);

            #pragma unroll
            for (int f = 0; f < 2; f++) {
                f32x4 S[4];
                #pragma unroll
                for (int g = 0; g < 4; g++) {
                    f32x4 z = {0, 0, 0, 0};
                    z = MFMA_BF16(qa[f][0], kf[g][0], z, 0, 0, 0);
                    z = MFMA_BF16(qa[f][1], kf[g][1], z, 0, 0, 0);
                    S[g] = z;
                }
                #pragma unroll
                for (int g = 0; g < 4; g++)
                    #pragma unroll
                    for (int r = 0; r < 4; r++)
                        plds[w][quad * 4 + r][g * 16 + l16] =
                            (__bf16)__builtin_amdgcn_exp2f(S[g][r]);
                asm volatile("s_waitcnt lgkmcnt(0)" ::: "memory");
                bf16x8 pa0 = *(const bf16x8*)&plds[w][l16][quad * 8];
                bf16x8 pa1 = *(const bf16x8*)&plds[w][l16][32 + quad * 8];
                #pragma unroll
                for (int n = 0; n < 4; n++) {
                    O[f][n] = MFMA_BF16(pa0, vf[n][0], O[f][n], 0, 0, 0);
                    O[f][n] = MFMA_BF16(pa1, vf[n][1], O[f][n], 0, 0, 0);
                }
                L[f] = MFMA_BF16(pa0, ones, L[f], 0, 0, 0);
                L[f] = MFMA_BF16(pa1, ones, L[f], 0, 0, 0);
            }
        }
    }

    #pragma unroll
    for (int f = 0; f < 2; f++) {
        float inv[4];
        #pragma unroll
        for (int r = 0; r < 4; r++) inv[r] = 1.0f / L[f][r];
        #pragma unroll
        for (int n = 0; n < 4; n++)
            #pragma unroll
            for (int r = 0; r < 4; r++) {
                size_t row = (size_t)(b * N_SEQ + qrow + f * 16 + quad * 4 + r);
                attn[row * 512 + h * DH + n * 16 + l16] = (__bf16)(O[f][n][r] * inv[r]);
            }
    }
}

extern "C" void kernel_launch(void* const* d_in, const int* in_sizes, int n_in,
                              void* d_out, int out_size, void* d_ws, size_t ws_size,
                              hipStream_t stream) {
    const float* x     = (const float*)d_in[0];
    const float* gamma = (const float*)d_in[1];
    const float* w_qkv = (const float*)d_in[2];
    const float* w_out = (const float*)d_in[3];
    float* out = (float*)d_out;

    // workspace (bf16): Abf 8.4MB (attnb aliases it after gemm1) | Wqkvt 1.5 |
    // Woutt 0.5 | qkvb 25.2 (dead after prep) | Qb,Kf,Vf 8.4 each.  ~61 MB (proven).
    __bf16* Abf   = (__bf16*)d_ws;
    __bf16* Wqkvt = Abf + (size_t)ROWS * DIM;
    __bf16* Woutt = Wqkvt + (size_t)QKV_N * DIM;
    __bf16* qkvb  = Woutt + (size_t)DIM * DIM;
    __bf16* attnb = qkvb;
    __bf16* Qb    = qkvb + (size_t)ROWS * QKV_N;
    __bf16* Kf    = Qb + (size_t)NH * B_SZ * N_SEQ * DH;
    __bf16* Vf    = Kf + (size_t)NH * B_SZ * N_SEQ * DH;

    rmscast_kernel<<<ROWS, 64, 0, stream>>>(x, gamma, Abf);
    tcast2_kernel<<<dim3(32, 8), 256, 0, stream>>>(w_qkv, w_out, Wqkvt, Woutt);
    gemm_bf16_kernel<QKV_N, __bf16><<<dim3(QKV_N / 128, ROWS / 128), 256, 0, stream>>>(
        Abf, Wqkvt, qkvb);
    prep_kernel<<<1024, 256, 0, stream>>>(qkvb, Qb, Kf, Vf);
    attn_mfma_kernel<<<512, 256, 0, stream>>>(Qb, Kf, Vf, attnb);
    gemm_bf16_kernel<DIM, float><<<dim3(DIM / 128, ROWS / 128), 256, 0, stream>>>(
        attnb, Woutt, out);
}

// Round 10
// 166.329 us; speedup vs baseline: 1.1981x; 1.0566x over previous
//
#include <hip/hip_runtime.h>
#include <hip/hip_bf16.h>
#include <cmath>

#define B_SZ 4
#define N_SEQ 2048
#define DIM 512
#define NH 8
#define DH 64
#define QKV_N 1536
#define ROWS (B_SZ * N_SEQ)   // 8192

typedef __bf16 bf16x8 __attribute__((ext_vector_type(8)));
typedef __bf16 bf16x4 __attribute__((ext_vector_type(4)));
typedef float  f32x4  __attribute__((ext_vector_type(4)));

#define GLOAD_LDS16(gp, lp)                                                     \
    __builtin_amdgcn_global_load_lds(                                           \
        (const __attribute__((address_space(1))) void*)(gp),                    \
        (__attribute__((address_space(3))) void*)(lp), 16, 0, 0)

#define MFMA_BF16 __builtin_amdgcn_mfma_f32_16x16x32_bf16

// ---------------- prelude: rmscast (blocks 0..2047, 4 rows each) + weight
// transpose-casts (blocks 2048..2303) in ONE launch.
__device__ __forceinline__ void tcast_tile(const float* __restrict__ W,
                                           __bf16* __restrict__ Wt,
                                           int K, int N, int n0, int k0, int t,
                                           float (*Ls)[68]) {
    const int tx = t & 15, ty = t >> 4;
    #pragma unroll
    for (int i = 0; i < 4; i++) {
        int k = ty + i * 16;
        float4 v = *(const float4*)&W[(size_t)(k0 + k) * N + n0 + tx * 4];
        *(float4*)&Ls[k][tx * 4] = v;
    }
    __syncthreads();
    const int nrow = t >> 2, seg = (t & 3) * 16;
    bf16x8 o0, o1;
    #pragma unroll
    for (int j = 0; j < 8; j++) o0[j] = (__bf16)Ls[seg + j][nrow];
    #pragma unroll
    for (int j = 0; j < 8; j++) o1[j] = (__bf16)Ls[seg + 8 + j][nrow];
    *(bf16x8*)&Wt[(size_t)(n0 + nrow) * K + k0 + seg]     = o0;
    *(bf16x8*)&Wt[(size_t)(n0 + nrow) * K + k0 + seg + 8] = o1;
}

__global__ __launch_bounds__(256) void prelude_kernel(const float* __restrict__ x,
                                                      const float* __restrict__ gamma,
                                                      const float* __restrict__ w_qkv,
                                                      const float* __restrict__ w_out,
                                                      __bf16* __restrict__ A,
                                                      __bf16* __restrict__ Wqkvt,
                                                      __bf16* __restrict__ Woutt) {
    __shared__ float Ls[64][68];
    const int bx = blockIdx.x, t = threadIdx.x;
    if (bx < 2048) {
        // rms-norm + gamma + bf16 cast; one wave per row, 4 rows per block
        const int row  = bx * 4 + (t >> 6);
        const int lane = t & 63;
        const float4* xr = (const float4*)(x + (size_t)row * DIM);
        float4 a = xr[lane];
        float4 b = xr[lane + 64];
        float ss = a.x*a.x + a.y*a.y + a.z*a.z + a.w*a.w
                 + b.x*b.x + b.y*b.y + b.z*b.z + b.w*b.w;
        #pragma unroll
        for (int off = 32; off > 0; off >>= 1) ss += __shfl_xor(ss, off, 64);
        float s = 22.62741699796952f / fmaxf(sqrtf(ss), 1e-8f);
        const float4* gr = (const float4*)gamma;
        float4 g1 = gr[lane], g2 = gr[lane + 64];
        bf16x4 o1 = { (__bf16)(a.x*g1.x*s), (__bf16)(a.y*g1.y*s),
                      (__bf16)(a.z*g1.z*s), (__bf16)(a.w*g1.w*s) };
        bf16x4 o2 = { (__bf16)(b.x*g2.x*s), (__bf16)(b.y*g2.y*s),
                      (__bf16)(b.z*g2.z*s), (__bf16)(b.w*g2.w*s) };
        *(bf16x4*)(A + (size_t)row * DIM + lane * 4)       = o1;
        *(bf16x4*)(A + (size_t)row * DIM + 256 + lane * 4) = o2;
    } else {
        const int idx = bx - 2048;          // 0..255
        const int k0 = (idx >> 5) * 64, c = idx & 31;
        if (c < 24) tcast_tile(w_qkv, Wqkvt, DIM, QKV_N, c * 64, k0, t, Ls);
        else        tcast_tile(w_out, Woutt, DIM, DIM, (c - 24) * 64, k0, t, Ls);
    }
}

// ---------------- bf16 MFMA GEMM (m97 structure): C[M,N] = A[M,512] @ Bt[N,512]^T
template <int N, typename OutT>
__global__ __launch_bounds__(256) void gemm_bf16_kernel(const __bf16* __restrict__ A,
                                                        const __bf16* __restrict__ Bt,
                                                        OutT* __restrict__ C) {
    __shared__ __bf16 As[128 * 32];
    __shared__ __bf16 Bs[128 * 32];
    const int t = threadIdx.x;
    const int lane = t & 63;
    const int w = t >> 6;
    const int l16 = lane & 15, quad = lane >> 4;
    const int wr = w >> 1, wc = w & 1;
    const int row0 = blockIdx.y * 128, col0 = blockIdx.x * 128;

    f32x4 acc[4][4] = {};

    const int r0a = t >> 2,         ks0 = (t & 3) * 8;
    const int r1a = (t + 256) >> 2, ks1 = (t & 3) * 8;

    for (int kt = 0; kt < DIM; kt += 32) {
        __syncthreads();
        GLOAD_LDS16(A  + (size_t)(row0 + r0a) * DIM + kt + ks0, As + t * 8);
        GLOAD_LDS16(A  + (size_t)(row0 + r1a) * DIM + kt + ks1, As + (t + 256) * 8);
        GLOAD_LDS16(Bt + (size_t)(col0 + r0a) * DIM + kt + ks0, Bs + t * 8);
        GLOAD_LDS16(Bt + (size_t)(col0 + r1a) * DIM + kt + ks1, Bs + (t + 256) * 8);
        __syncthreads();
        bf16x8 af[4], bfr[4];
        #pragma unroll
        for (int mi = 0; mi < 4; mi++)
            af[mi] = *(const bf16x8*)(As + (wr * 64 + mi * 16 + l16) * 32 + quad * 8);
        #pragma unroll
        for (int ni = 0; ni < 4; ni++)
            bfr[ni] = *(const bf16x8*)(Bs + (wc * 64 + ni * 16 + l16) * 32 + quad * 8);
        #pragma unroll
        for (int mi = 0; mi < 4; mi++)
            #pragma unroll
            for (int ni = 0; ni < 4; ni++)
                acc[mi][ni] = MFMA_BF16(af[mi], bfr[ni], acc[mi][ni], 0, 0, 0);
    }
    #pragma unroll
    for (int mi = 0; mi < 4; mi++) {
        #pragma unroll
        for (int ni = 0; ni < 4; ni++) {
            #pragma unroll
            for (int r = 0; r < 4; r++) {
                int m = row0 + wr * 64 + mi * 16 + quad * 4 + r;
                int n = col0 + wc * 64 + ni * 16 + l16;
                if constexpr (sizeof(OutT) == 4) {
                    C[(size_t)m * N + n] = acc[mi][ni][r];
                } else {
                    C[(size_t)m * N + n] = (__bf16)acc[mi][ni][r];
                }
            }
        }
    }
}

// ---------------- out-projection GEMM, 64x128 tile (grid 4x128 = 512 blocks ->
// 2 blocks/CU vs 1 for the 128x128 version; latency hiding via TLP).
__global__ __launch_bounds__(256) void gemm_out_kernel(const __bf16* __restrict__ A,
                                                       const __bf16* __restrict__ Bt,
                                                       float* __restrict__ C) {
    __shared__ __bf16 As[64 * 32];     // 4 KB
    __shared__ __bf16 Bs[128 * 32];    // 8 KB
    const int t = threadIdx.x;
    const int lane = t & 63;
    const int w = t >> 6;
    const int l16 = lane & 15, quad = lane >> 4;
    const int wr = w >> 1, wc = w & 1;   // wave tile: 32 rows x 64 cols
    const int row0 = blockIdx.y * 64, col0 = blockIdx.x * 128;

    f32x4 acc[2][4] = {};

    const int r0a = t >> 2, ks0 = (t & 3) * 8;
    const int r1a = (t + 256) >> 2;

    for (int kt = 0; kt < DIM; kt += 32) {
        __syncthreads();
        GLOAD_LDS16(A  + (size_t)(row0 + r0a) * DIM + kt + ks0, As + t * 8);
        GLOAD_LDS16(Bt + (size_t)(col0 + r0a) * DIM + kt + ks0, Bs + t * 8);
        GLOAD_LDS16(Bt + (size_t)(col0 + r1a) * DIM + kt + ks0, Bs + (t + 256) * 8);
        __syncthreads();
        bf16x8 af[2], bfr[4];
        #pragma unroll
        for (int mi = 0; mi < 2; mi++)
            af[mi] = *(const bf16x8*)(As + (wr * 32 + mi * 16 + l16) * 32 + quad * 8);
        #pragma unroll
        for (int ni = 0; ni < 4; ni++)
            bfr[ni] = *(const bf16x8*)(Bs + (wc * 64 + ni * 16 + l16) * 32 + quad * 8);
        #pragma unroll
        for (int mi = 0; mi < 2; mi++)
            #pragma unroll
            for (int ni = 0; ni < 4; ni++)
                acc[mi][ni] = MFMA_BF16(af[mi], bfr[ni], acc[mi][ni], 0, 0, 0);
    }
    #pragma unroll
    for (int mi = 0; mi < 2; mi++)
        #pragma unroll
        for (int ni = 0; ni < 4; ni++)
            #pragma unroll
            for (int r = 0; r < 4; r++) {
                int m = row0 + wr * 32 + mi * 16 + quad * 4 + r;
                int n = col0 + wc * 64 + ni * 16 + l16;
                C[(size_t)m * 512 + n] = acc[mi][ni][r];
            }
}

// ---------------- Prep: fused RoPE + head-major bf16 Q + PRE-FRAGMENTED K and V^T.
// Q scale = 0.125 * log2(e): attention uses raw v_exp_f32 (exp2) directly.
__global__ __launch_bounds__(256) void prep_kernel(const __bf16* __restrict__ qkvb,
                                                   __bf16* __restrict__ Qb,
                                                   __bf16* __restrict__ Kf,
                                                   __bf16* __restrict__ Vf) {
    const int bx = blockIdx.x;   // bh*32 + ntile
    const int nt = bx & 31;
    const int bh = bx >> 5;
    const int b  = bh >> 3;
    const int h  = bh & 7;
    const int t  = threadIdx.x;
    const float QSCALE = 0.18033688011112042f;   // 0.125 * log2(e)

    {   // Q/K rope: thread t -> row r = t>>2, dims d0 = (t&3)*16 (8 pairs)
        const int r  = t >> 2;
        const int d0 = (t & 3) << 4;
        const int pos = nt * 64 + r;
        const __bf16* qp = qkvb + (size_t)(b * N_SEQ + pos) * QKV_N + h * DH + d0;

        union Pack { __bf16 h[16]; uint4 u[2]; };
        Pack qi, ki, qo, ko;
        qi.u[0] = ((const uint4*)qp)[0];         qi.u[1] = ((const uint4*)qp)[1];
        ki.u[0] = ((const uint4*)(qp + 512))[0]; ki.u[1] = ((const uint4*)(qp + 512))[1];

        #pragma unroll
        for (int i = 0; i < 8; i++) {
            int p = (d0 >> 1) + i;
            float inv = exp2f(-0.41524101186092028f * (float)p);  // 10000^(-p/32)
            float ang = (float)pos * inv;
            float sn, cs;
            sincosf(ang, &sn, &cs);
            float qe = (float)qi.h[2*i], qd = (float)qi.h[2*i+1];
            float ke = (float)ki.h[2*i], kd = (float)ki.h[2*i+1];
            qo.h[2*i]   = (__bf16)(QSCALE * (qe * cs - qd * sn));
            qo.h[2*i+1] = (__bf16)(QSCALE * (qd * cs + qe * sn));
            ko.h[2*i]   = (__bf16)(ke * cs - kd * sn);
            ko.h[2*i+1] = (__bf16)(kd * cs + ke * sn);
        }
        // Q: row-major
        uint4* qd_ = (uint4*)(Qb + ((size_t)bh * N_SEQ + pos) * DH + d0);
        qd_[0] = qo.u[0]; qd_[1] = qo.u[1];
        // K: fragmented (chunk (g*2+c), elem (quad*16+kl)*8+j)
        const int group = r >> 4, kl = r & 15;
        const int c = d0 >> 5, quad = (d0 & 31) >> 3;
        __bf16* kdst = Kf + ((size_t)bh * 32 + nt) * 4096
                          + (group * 2 + c) * 512 + (quad * 16 + kl) * 8;
        *(uint4*)kdst         = ko.u[0];
        *(uint4*)(kdst + 128) = ko.u[1];   // quad+1
    }

    {   // V: wave w -> keys w*16..+15, lane = dim 0..63; write fragmented V^T
        const int w = t >> 6, lane = t & 63;
        union Pack { __bf16 h[16]; uint4 u[2]; };
        Pack v;
        #pragma unroll
        for (int j = 0; j < 16; j++) {
            int row = nt * 64 + w * 16 + j;
            v.h[j] = qkvb[(size_t)(b * N_SEQ + row) * QKV_N + 1024 + h * DH + lane];
        }
        const int ng = lane >> 4, vl = lane & 15;
        __bf16* vdst = Vf + ((size_t)bh * 32 + nt) * 4096
                          + (ng * 2 + (w >> 1)) * 512 + (((w & 1) * 2) * 16 + vl) * 8;
        *(uint4*)vdst         = v.u[0];
        *(uint4*)(vdst + 128) = v.u[1];    // quad+1
    }
}

// ---------------- MFMA flash attention (R9 structure; compiler-managed lgkmcnt).
// 128-key tiles, double-buffered DMA with prefetch-before-wait vmcnt(8). The P
// roundtrip relies on the compiler's precise per-wave DS dependency waits (no
// asm drain -> allows cross-(f,half) software pipelining by the scheduler).
__global__ __launch_bounds__(256, 2) void attn_mfma_kernel(const __bf16* __restrict__ Qb,
                                                           const __bf16* __restrict__ Kf,
                                                           const __bf16* __restrict__ Vf,
                                                           __bf16* __restrict__ attn) {
    __shared__ __bf16 kv[2][16384];      // [buf][K0 K1 V0 V1]  = 64 KB
    __shared__ __bf16 plds[4][16][68];   // per-wave P buffer   = 8.7 KB

    const int t    = threadIdx.x;
    const int w    = t >> 6;
    const int lane = t & 63;
    const int l16  = lane & 15;
    const int quad = lane >> 4;

    const int bx = blockIdx.x;     // qc*32 + bh
    const int bh = bx & 31;
    const int qc = bx >> 5;        // 0..15
    const int b  = bh >> 3;
    const int h  = bh & 7;

    const int qrow = qc * 128 + w * 32;
    const __bf16* Qh = Qb + ((size_t)bh * N_SEQ + qrow) * DH;
    const __bf16* Kt = Kf + (size_t)bh * 32 * 4096;
    const __bf16* Vt = Vf + (size_t)bh * 32 * 4096;

    bf16x8 qa[2][2];
    #pragma unroll
    for (int f = 0; f < 2; f++) {
        qa[f][0] = *(const bf16x8*)(Qh + (size_t)(f * 16 + l16) * DH + quad * 8);
        qa[f][1] = *(const bf16x8*)(Qh + (size_t)(f * 16 + l16) * DH + 32 + quad * 8);
    }

    bf16x8 ones;
    #pragma unroll
    for (int i = 0; i < 8; i++) ones[i] = (__bf16)1.0f;

    f32x4 O[2][4] = {};
    f32x4 L[2] = {};

    auto dma_tile = [&](int tt, int bb) {    // tt = 128-key tile index (0..15)
        const __bf16* kss = Kt + (size_t)tt * 8192;
        const __bf16* vss = Vt + (size_t)tt * 8192;
        #pragma unroll
        for (int seg = 0; seg < 2; seg++) {
            GLOAD_LDS16(kss + seg * 4096 + w * 512 + lane * 8,
                        &kv[bb][seg * 4096 + w * 512 + lane * 8]);
            GLOAD_LDS16(kss + seg * 4096 + (w + 4) * 512 + lane * 8,
                        &kv[bb][seg * 4096 + (w + 4) * 512 + lane * 8]);
            GLOAD_LDS16(vss + seg * 4096 + w * 512 + lane * 8,
                        &kv[bb][8192 + seg * 4096 + w * 512 + lane * 8]);
            GLOAD_LDS16(vss + seg * 4096 + (w + 4) * 512 + lane * 8,
                        &kv[bb][8192 + seg * 4096 + (w + 4) * 512 + lane * 8]);
        }
    };

    dma_tile(0, 0);
    for (int tt = 0; tt < 16; tt++) {
        const int cur = tt & 1;
        __syncthreads();                       // all waves done with buf[cur^1]
        if (tt + 1 < 16) {
            dma_tile(tt + 1, cur ^ 1);         // prefetch (8 loads stay in flight)
            asm volatile("s_waitcnt vmcnt(8)" ::: "memory");   // drain tile tt only
        } else {
            asm volatile("s_waitcnt vmcnt(0)" ::: "memory");
        }
        __syncthreads();                       // publish tile tt to all waves

        #pragma unroll
        for (int hh = 0; hh < 2; hh++) {       // two 64-key halves of the tile
            const __bf16* kb = kv[cur] + hh * 4096;
            const __bf16* vb = kv[cur] + 8192 + hh * 4096;

            bf16x8 kf[4][2];
            #pragma unroll
            for (int g = 0; g < 4; g++)
                #pragma unroll
                for (int c = 0; c < 2; c++)
                    kf[g][c] = *(const bf16x8*)(kb + (g * 2 + c) * 512 + lane * 8);
            bf16x8 vf[4][2];
            #pragma unroll
            for (int n = 0; n < 4; n++)
                #pragma unroll
                for (int kc = 0; kc < 2; kc++)
                    vf[n][kc] = *(const bf16x8*)(vb + (n * 2 + kc) * 512 + lane * 8);

            #pragma unroll
            for (int f = 0; f < 2; f++) {
                f32x4 S[4];
                #pragma unroll
                for (int g = 0; g < 4; g++) {
                    f32x4 z = {0, 0, 0, 0};
                    z = MFMA_BF16(qa[f][0], kf[g][0], z, 0, 0, 0);
                    z = MFMA_BF16(qa[f][1], kf[g][1], z, 0, 0, 0);
                    S[g] = z;
                }
                #pragma unroll
                for (int g = 0; g < 4; g++)
                    #pragma unroll
                    for (int r = 0; r < 4; r++)
                        plds[w][quad * 4 + r][g * 16 + l16] =
                            (__bf16)__builtin_amdgcn_exp2f(S[g][r]);
                // compiler inserts the precise lgkmcnt wait for this RAW
                bf16x8 pa0 = *(const bf16x8*)&plds[w][l16][quad * 8];
                bf16x8 pa1 = *(const bf16x8*)&plds[w][l16][32 + quad * 8];
                #pragma unroll
                for (int n = 0; n < 4; n++) {
                    O[f][n] = MFMA_BF16(pa0, vf[n][0], O[f][n], 0, 0, 0);
                    O[f][n] = MFMA_BF16(pa1, vf[n][1], O[f][n], 0, 0, 0);
                }
                L[f] = MFMA_BF16(pa0, ones, L[f], 0, 0, 0);
                L[f] = MFMA_BF16(pa1, ones, L[f], 0, 0, 0);
            }
        }
    }

    #pragma unroll
    for (int f = 0; f < 2; f++) {
        float inv[4];
        #pragma unroll
        for (int r = 0; r < 4; r++) inv[r] = 1.0f / L[f][r];
        #pragma unroll
        for (int n = 0; n < 4; n++)
            #pragma unroll
            for (int r = 0; r < 4; r++) {
                size_t row = (size_t)(b * N_SEQ + qrow + f * 16 + quad * 4 + r);
                attn[row * 512 + h * DH + n * 16 + l16] = (__bf16)(O[f][n][r] * inv[r]);
            }
    }
}

extern "C" void kernel_launch(void* const* d_in, const int* in_sizes, int n_in,
                              void* d_out, int out_size, void* d_ws, size_t ws_size,
                              hipStream_t stream) {
    const float* x     = (const float*)d_in[0];
    const float* gamma = (const float*)d_in[1];
    const float* w_qkv = (const float*)d_in[2];
    const float* w_out = (const float*)d_in[3];
    float* out = (float*)d_out;

    // workspace (bf16): Abf 8.4MB (attnb aliases it after gemm1) | Wqkvt 1.5 |
    // Woutt 0.5 | qkvb 25.2 (dead after prep) | Qb,Kf,Vf 8.4 each.  ~61 MB (proven).
    __bf16* Abf   = (__bf16*)d_ws;
    __bf16* Wqkvt = Abf + (size_t)ROWS * DIM;
    __bf16* Woutt = Wqkvt + (size_t)QKV_N * DIM;
    __bf16* qkvb  = Woutt + (size_t)DIM * DIM;
    __bf16* attnb = qkvb;
    __bf16* Qb    = qkvb + (size_t)ROWS * QKV_N;
    __bf16* Kf    = Qb + (size_t)NH * B_SZ * N_SEQ * DH;
    __bf16* Vf    = Kf + (size_t)NH * B_SZ * N_SEQ * DH;

    prelude_kernel<<<2304, 256, 0, stream>>>(x, gamma, w_qkv, w_out,
                                             Abf, Wqkvt, Woutt);
    gemm_bf16_kernel<QKV_N, __bf16><<<dim3(QKV_N / 128, ROWS / 128), 256, 0, stream>>>(
        Abf, Wqkvt, qkvb);
    prep_kernel<<<1024, 256, 0, stream>>>(qkvb, Qb, Kf, Vf);
    attn_mfma_kernel<<<512, 256, 0, stream>>>(Qb, Kf, Vf, attnb);
    gemm_out_kernel<<<dim3(4, 128), 256, 0, stream>>>(attnb, Woutt, out);
}